// Round 1
// baseline (715.276 us; speedup 1.0000x reference)
//
#include <hip/hip_runtime.h>
#include <math.h>

#define NSEQ   256          // B*P
#define SLEN   48
#define DIN    64
#define DOUT   127
#define NEGINF -1e9f

// Kernel 1: continuous-time embedding  z[ns][i], layout (N*S, 64)
__global__ void embed_k(const float* __restrict__ values,
                        const float* __restrict__ times,
                        const float* __restrict__ omega,
                        const float* __restrict__ alpha,
                        float* __restrict__ z) {
    int idx = blockIdx.x * 256 + threadIdx.x;   // over N*S*64
    int i  = idx & 63;
    int ns = idx >> 6;
    if (ns >= NSEQ * SLEN) return;
    float t = times[ns];
    float r;
    if (i == 0)       r = omega[0] * t + alpha[0];
    else if (i < 63)  r = sinf(t * omega[i] + alpha[i]);
    else              r = values[ns];
    z[idx] = r;
}

// Kernel 2: one wave per (n, d).  Block = 4 waves = 4 consecutive d for one n.
__global__ __launch_bounds__(256) void filter_k(
    const float* __restrict__ z,      // (N*S, 64)
    const int*   __restrict__ mask,   // (N, S) as int32
    const float* __restrict__ W1, const float* __restrict__ b1,
    const float* __restrict__ W2, const float* __restrict__ b2,
    float* __restrict__ out)          // (N, 128)
{
    const int n    = blockIdx.y;
    const int dq   = blockIdx.x;          // 0..31
    const int wave = threadIdx.x >> 6;
    const int lane = threadIdx.x & 63;    // j (output feature within filter)
    const int d    = dq * 4 + wave;       // 0..127

    __shared__ __align__(16) float z_lds[SLEN * DIN];        // 12 KB
    __shared__ __align__(16) float h_lds[4][SLEN * DIN];     // 48 KB

    // cooperative load of z[n] (48x64)
    for (int k = threadIdx.x; k < SLEN * DIN; k += 256)
        z_lds[k] = z[n * SLEN * DIN + k];
    __syncthreads();

    if (d < DOUT) {
        float acc[SLEN];

        // ---- layer 1: h[s][j] = relu( sum_i z[s][i] * W1[d][i][j] + b1[d][j] )
        const float* __restrict__ W1d = W1 + d * DIN * DIN;
        const float bj1 = b1[d * DIN + lane];
        #pragma unroll
        for (int s = 0; s < SLEN; ++s) acc[s] = bj1;
        for (int i4 = 0; i4 < DIN / 4; ++i4) {
            float w0 = W1d[(i4 * 4 + 0) * DIN + lane];
            float w1 = W1d[(i4 * 4 + 1) * DIN + lane];
            float w2 = W1d[(i4 * 4 + 2) * DIN + lane];
            float w3 = W1d[(i4 * 4 + 3) * DIN + lane];
            #pragma unroll
            for (int s = 0; s < SLEN; ++s) {
                float4 zq = *(const float4*)&z_lds[s * DIN + i4 * 4];
                acc[s] = fmaf(zq.x, w0, acc[s]);
                acc[s] = fmaf(zq.y, w1, acc[s]);
                acc[s] = fmaf(zq.z, w2, acc[s]);
                acc[s] = fmaf(zq.w, w3, acc[s]);
            }
        }
        // relu -> per-wave LDS buffer (wave-synchronous: same-wave ds ordering)
        float* __restrict__ hrow = &h_lds[wave][0];
        #pragma unroll
        for (int s = 0; s < SLEN; ++s)
            hrow[s * DIN + lane] = fmaxf(acc[s], 0.f);

        // ---- layer 2: logits[s][j] = sum_i h[s][i] * W2[d][i][j] + b2[d][j]
        const float* __restrict__ W2d = W2 + d * DIN * DIN;
        const float bj2 = b2[d * DIN + lane];
        #pragma unroll
        for (int s = 0; s < SLEN; ++s) acc[s] = bj2;
        for (int i4 = 0; i4 < DIN / 4; ++i4) {
            float w0 = W2d[(i4 * 4 + 0) * DIN + lane];
            float w1 = W2d[(i4 * 4 + 1) * DIN + lane];
            float w2 = W2d[(i4 * 4 + 2) * DIN + lane];
            float w3 = W2d[(i4 * 4 + 3) * DIN + lane];
            #pragma unroll
            for (int s = 0; s < SLEN; ++s) {
                float4 hq = *(const float4*)&hrow[s * DIN + i4 * 4];
                acc[s] = fmaf(hq.x, w0, acc[s]);
                acc[s] = fmaf(hq.y, w1, acc[s]);
                acc[s] = fmaf(hq.z, w2, acc[s]);
                acc[s] = fmaf(hq.w, w3, acc[s]);
            }
        }

        // ---- mask + softmax over s (each lane owns all 48 s for its j)
        #pragma unroll
        for (int s = 0; s < SLEN; ++s)
            if (mask[n * SLEN + s] == 0) acc[s] = NEGINF;
        float mx = acc[0];
        #pragma unroll
        for (int s = 1; s < SLEN; ++s) mx = fmaxf(mx, acc[s]);
        float sum = 0.f;
        #pragma unroll
        for (int s = 0; s < SLEN; ++s) { acc[s] = __expf(acc[s] - mx); sum += acc[s]; }
        float inv = 1.f / sum;

        // ---- h_c[n,d] = sum_s sum_j w[s][j] * z[s][j]
        float part = 0.f;
        #pragma unroll
        for (int s = 0; s < SLEN; ++s)
            part = fmaf(acc[s] * inv, z_lds[s * DIN + lane], part);
        #pragma unroll
        for (int off = 32; off >= 1; off >>= 1)
            part += __shfl_xor(part, off);
        if (lane == 0) out[n * 128 + d] = part;
    } else {
        // d == 127: mask-any channel
        if (lane == 0) {
            int any = 0;
            for (int s = 0; s < SLEN; ++s) any |= mask[n * SLEN + s];
            out[n * 128 + 127] = any ? 1.f : 0.f;
        }
    }
}

extern "C" void kernel_launch(void* const* d_in, const int* in_sizes, int n_in,
                              void* d_out, int out_size, void* d_ws, size_t ws_size,
                              hipStream_t stream) {
    const float* values = (const float*)d_in[0];
    const float* times  = (const float*)d_in[1];
    const int*   mask   = (const int*)d_in[2];
    const float* omega  = (const float*)d_in[3];
    const float* alpha  = (const float*)d_in[4];
    const float* W1     = (const float*)d_in[5];
    const float* b1     = (const float*)d_in[6];
    const float* W2     = (const float*)d_in[7];
    const float* b2     = (const float*)d_in[8];
    float* out = (float*)d_out;
    float* z   = (float*)d_ws;   // 12288*64 f32 = 3.1 MB

    embed_k<<<dim3((NSEQ * SLEN * DIN + 255) / 256), dim3(256), 0, stream>>>(
        values, times, omega, alpha, z);
    filter_k<<<dim3(32, NSEQ), dim3(256), 0, stream>>>(
        z, mask, W1, b1, W2, b2, out);
}

// Round 3
// 77.105 us; speedup vs baseline: 9.2767x; 9.2767x over previous
//
#include <hip/hip_runtime.h>
#include <math.h>

#define NSEQ 256
#define SLEN 48
#define DIN  64
#define NCH  16

typedef _Float16 half8  __attribute__((ext_vector_type(8)));
typedef __fp16   fp16x2 __attribute__((ext_vector_type(2)));
typedef float    f32x4  __attribute__((ext_vector_type(4)));

union U8 { _Float16 h[8]; uint4 u; };
union U2 { _Float16 h[4]; uint2 u; };

// ---------------- K1: mask bits + out[:,127] ----------------
__global__ __launch_bounds__(256) void mask_k(const int* __restrict__ mask,
                                              unsigned long long* __restrict__ mask64,
                                              float* __restrict__ out) {
    int wid  = (blockIdx.x * 256 + threadIdx.x) >> 6;   // one wave per n
    int lane = threadIdx.x & 63;
    if (wid >= NSEQ) return;
    int mv = (lane < SLEN) ? mask[wid * SLEN + lane] : 0;
    unsigned long long b = __ballot(mv != 0);
    if (lane == 0) { mask64[wid] = b; out[wid * 128 + 127] = b ? 1.f : 0.f; }
}

// ---------------- K2: W -> f16 A-fragment layout (A = W^T) ----------------
// dest elem: Wf[((d*8 + mt*2+kt)*64 + lane)*8 + e] = W[d][32kt+8g+e][16mt+c]
__global__ __launch_bounds__(256) void wprep_k(const float* __restrict__ W,
                                               unsigned short* __restrict__ Wf) {
    __shared__ float wl[DIN * DIN];
    int d = blockIdx.x;
    const float* src = W + (size_t)d * DIN * DIN;
    for (int k = threadIdx.x; k < DIN * DIN / 4; k += 256)
        ((float4*)wl)[k] = ((const float4*)src)[k];
    __syncthreads();
    for (int rr = 0; rr < 2; ++rr) {
        int idx = threadIdx.x * 2 + rr;          // 0..511
        int fid = idx >> 6, l = idx & 63;
        int mt = fid >> 1, kt = fid & 1, g = l >> 4, c = l & 15;
        U8 t;
        #pragma unroll
        for (int e = 0; e < 8; ++e)
            t.h[e] = (_Float16)wl[(32 * kt + 8 * g + e) * DIN + (16 * mt + c)];
        *(uint4*)(Wf + ((size_t)(d * 8 + fid) * 64 + l) * 8) = t.u;
    }
}

// ---------------- K3: embedding -> f16, row-swizzled ----------------
// zh layout: per (n,s) row of 64 f16 (128B); 16B chunk ch stored at ch^(s&7)
__global__ __launch_bounds__(256) void embed_k(const float* __restrict__ values,
                                               const float* __restrict__ times,
                                               const float* __restrict__ omega,
                                               const float* __restrict__ alpha,
                                               unsigned short* __restrict__ zh) {
    int id = blockIdx.x * 256 + threadIdx.x;     // (ns, chunk)
    int ch = id & 7, ns = id >> 3;
    if (ns >= NSEQ * SLEN) return;
    int s = ns % SLEN;
    float t = times[ns];
    U8 o;
    #pragma unroll
    for (int e = 0; e < 8; ++e) {
        int i = ch * 8 + e;
        float r;
        if (i == 0)       r = omega[0] * t + alpha[0];
        else if (i == 63) r = values[ns];
        else              r = __sinf(t * omega[i] + alpha[i]);
        o.h[e] = (_Float16)r;
    }
    int csw = ch ^ (s & 7);
    *(uint4*)(zh + (size_t)ns * 64 + csw * 8) = o.u;
}

// ---------------- K4: main fused kernel ----------------
// block = 4 waves (4 consecutive d), loops NCH n's. z double-buffered in LDS.
__global__ __launch_bounds__(256, 2) void filter_k(
    const unsigned short* __restrict__ zh,
    const unsigned long long* __restrict__ mask64,
    const unsigned short* __restrict__ w1f, const unsigned short* __restrict__ w2f,
    const float* __restrict__ b1, const float* __restrict__ b2,
    float* __restrict__ out)
{
    const int tid = threadIdx.x;
    const int w = tid >> 6, lane = tid & 63;
    const int g = lane >> 4, c = lane & 15;
    const int d = blockIdx.y * 4 + w;
    const bool valid = (d < 127);
    const int nbase = blockIdx.x * NCH;

    __shared__ __align__(16) unsigned short zbuf[2][SLEN * DIN];  // 2 x 6KB
    __shared__ __align__(16) unsigned short hbuf[4][SLEN * DIN];  // 4 x 6KB

    // per-d constants (fragments + biases)
    half8 w1fr[8], w2fr[8];
    float b1v[16], b2v[16];
    if (valid) {
        #pragma unroll
        for (int f = 0; f < 8; ++f) {
            w1fr[f] = *(const half8*)(w1f + ((size_t)(d * 8 + f) * 64 + lane) * 8);
            w2fr[f] = *(const half8*)(w2f + ((size_t)(d * 8 + f) * 64 + lane) * 8);
        }
        #pragma unroll
        for (int mt = 0; mt < 4; ++mt)
            #pragma unroll
            for (int r = 0; r < 4; ++r) {
                b1v[mt * 4 + r] = b1[d * DIN + 16 * mt + 4 * g + r];
                b2v[mt * 4 + r] = b2[d * DIN + 16 * mt + 4 * g + r];
            }
    }

    // hoisted LDS element offsets
    int zoff[2][3];   // b128 B-frag reads (z and h): row s=16st+c, chunk (4kt+g)^(s&7)
    #pragma unroll
    for (int kt = 0; kt < 2; ++kt)
        #pragma unroll
        for (int st = 0; st < 3; ++st) {
            int s = 16 * st + c;
            zoff[kt][st] = s * 64 + (((4 * kt + g) ^ (s & 7)) << 3);
        }
    int off2[4][3];   // b64: (row s, cols 16*q+4g+0..3), q = hm or jt
    #pragma unroll
    for (int q = 0; q < 4; ++q)
        #pragma unroll
        for (int st = 0; st < 3; ++st) {
            int s = 16 * st + c;
            off2[q][st] = s * 64 + ((((2 * q + (g >> 1)) ^ (s & 7))) << 3) + (g & 1) * 4;
        }

    // prologue staging (n0)
    uint4 st0, st1;
    st0 = *(const uint4*)(zh + (size_t)nbase * 3072 + tid * 8);
    if (tid < 128) st1 = *(const uint4*)(zh + (size_t)nbase * 3072 + (256 + tid) * 8);
    *(uint4*)(&zbuf[0][tid * 8]) = st0;
    if (tid < 128) *(uint4*)(&zbuf[0][(256 + tid) * 8]) = st1;

    int cur = 0;
    for (int ni = 0; ni < NCH; ++ni) {
        const int n = nbase + ni;
        __syncthreads();
        // issue next-tile loads early (T14: latency hides under compute)
        if (ni + 1 < NCH) {
            st0 = *(const uint4*)(zh + (size_t)(n + 1) * 3072 + tid * 8);
            if (tid < 128) st1 = *(const uint4*)(zh + (size_t)(n + 1) * 3072 + (256 + tid) * 8);
        }
        if (valid) {
            const unsigned short* zl = zbuf[cur];
            // ---- layer 1: H^T = W1^T x Z^T
            half8 zf[2][3];
            #pragma unroll
            for (int kt = 0; kt < 2; ++kt)
                #pragma unroll
                for (int stt = 0; stt < 3; ++stt)
                    zf[kt][stt] = *(const half8*)(zl + zoff[kt][stt]);
            f32x4 aH[4][3];
            #pragma unroll
            for (int hm = 0; hm < 4; ++hm)
                #pragma unroll
                for (int stt = 0; stt < 3; ++stt) {
                    aH[hm][stt] = (f32x4){b1v[hm * 4 + 0], b1v[hm * 4 + 1],
                                          b1v[hm * 4 + 2], b1v[hm * 4 + 3]};
                    #pragma unroll
                    for (int kt = 0; kt < 2; ++kt)
                        aH[hm][stt] = __builtin_amdgcn_mfma_f32_16x16x32_f16(
                            w1fr[hm * 2 + kt], zf[kt][stt], aH[hm][stt], 0, 0, 0);
                }
            // relu -> f16 -> per-wave LDS (same-wave ordering, no barrier)
            unsigned short* hb = hbuf[w];
            #pragma unroll
            for (int hm = 0; hm < 4; ++hm)
                #pragma unroll
                for (int stt = 0; stt < 3; ++stt) {
                    float r0 = fmaxf(aH[hm][stt][0], 0.f), r1 = fmaxf(aH[hm][stt][1], 0.f);
                    float r2 = fmaxf(aH[hm][stt][2], 0.f), r3 = fmaxf(aH[hm][stt][3], 0.f);
                    fp16x2 pk0 = __builtin_amdgcn_cvt_pkrtz(r0, r1);
                    fp16x2 pk1 = __builtin_amdgcn_cvt_pkrtz(r2, r3);
                    U2 p;
                    *(fp16x2*)&p.h[0] = pk0;
                    *(fp16x2*)&p.h[2] = pk1;
                    *(uint2*)(hb + off2[hm][stt]) = p.u;
                }
            // ---- layer 2: logits^T = W2^T x H^T
            half8 hf[2][3];
            #pragma unroll
            for (int kt = 0; kt < 2; ++kt)
                #pragma unroll
                for (int stt = 0; stt < 3; ++stt)
                    hf[kt][stt] = *(const half8*)(hb + zoff[kt][stt]);
            f32x4 aL[4][3];
            #pragma unroll
            for (int jt = 0; jt < 4; ++jt)
                #pragma unroll
                for (int stt = 0; stt < 3; ++stt) {
                    aL[jt][stt] = (f32x4){b2v[jt * 4 + 0], b2v[jt * 4 + 1],
                                          b2v[jt * 4 + 2], b2v[jt * 4 + 3]};
                    #pragma unroll
                    for (int kt = 0; kt < 2; ++kt)
                        aL[jt][stt] = __builtin_amdgcn_mfma_f32_16x16x32_f16(
                            w2fr[jt * 2 + kt], hf[kt][stt], aL[jt][stt], 0, 0, 0);
                }
            // ---- masked exp (no max-sub: |logits| small), in place
            unsigned long long mw = mask64[n];
            bool mb[3];
            #pragma unroll
            for (int stt = 0; stt < 3; ++stt) mb[stt] = (mw >> (16 * stt + c)) & 1ull;
            #pragma unroll
            for (int jt = 0; jt < 4; ++jt)
                #pragma unroll
                for (int stt = 0; stt < 3; ++stt)
                    #pragma unroll
                    for (int r = 0; r < 4; ++r) {
                        float x = __expf(aL[jt][stt][r]);
                        aL[jt][stt][r] = mb[stt] ? x : 0.f;
                    }
            // ---- denominators: sum over s (in-lane st + 16-lane butterfly)
            float den[16];
            #pragma unroll
            for (int jt = 0; jt < 4; ++jt)
                #pragma unroll
                for (int r = 0; r < 4; ++r)
                    den[jt * 4 + r] = aL[jt][0][r] + aL[jt][1][r] + aL[jt][2][r];
            #pragma unroll
            for (int i = 0; i < 16; ++i) {
                float v = den[i];
                v += __shfl_xor(v, 1); v += __shfl_xor(v, 2);
                v += __shfl_xor(v, 4); v += __shfl_xor(v, 8);
                den[i] = v;
            }
            // ---- h_c partial: sum e * z / den
            float part = 0.f;
            #pragma unroll
            for (int jt = 0; jt < 4; ++jt) {
                float rd0 = 0.f, rd1 = 0.f, rd2 = 0.f, rd3 = 0.f;
                #pragma unroll
                for (int stt = 0; stt < 3; ++stt) {
                    U2 zu;
                    zu.u = *(const uint2*)(zl + off2[jt][stt]);
                    rd0 += aL[jt][stt][0] * (float)zu.h[0];
                    rd1 += aL[jt][stt][1] * (float)zu.h[1];
                    rd2 += aL[jt][stt][2] * (float)zu.h[2];
                    rd3 += aL[jt][stt][3] * (float)zu.h[3];
                }
                part += rd0 * __builtin_amdgcn_rcpf(den[jt * 4 + 0]);
                part += rd1 * __builtin_amdgcn_rcpf(den[jt * 4 + 1]);
                part += rd2 * __builtin_amdgcn_rcpf(den[jt * 4 + 2]);
                part += rd3 * __builtin_amdgcn_rcpf(den[jt * 4 + 3]);
            }
            #pragma unroll
            for (int x = 1; x < 64; x <<= 1) part += __shfl_xor(part, x);
            if (lane == 0) out[n * 128 + d] = part;
        }
        // write-late: stage next tile into the other buffer
        if (ni + 1 < NCH) {
            *(uint4*)(&zbuf[cur ^ 1][tid * 8]) = st0;
            if (tid < 128) *(uint4*)(&zbuf[cur ^ 1][(256 + tid) * 8]) = st1;
        }
        cur ^= 1;
    }
}

extern "C" void kernel_launch(void* const* d_in, const int* in_sizes, int n_in,
                              void* d_out, int out_size, void* d_ws, size_t ws_size,
                              hipStream_t stream) {
    const float* values = (const float*)d_in[0];
    const float* times  = (const float*)d_in[1];
    const int*   mask   = (const int*)d_in[2];
    const float* omega  = (const float*)d_in[3];
    const float* alpha  = (const float*)d_in[4];
    const float* W1     = (const float*)d_in[5];
    const float* b1     = (const float*)d_in[6];
    const float* W2     = (const float*)d_in[7];
    const float* b2     = (const float*)d_in[8];
    float* out = (float*)d_out;

    unsigned short* zh  = (unsigned short*)d_ws;                       // 786432 f16
    unsigned short* w1f = zh + (size_t)NSEQ * SLEN * DIN;              // 520192 f16
    unsigned short* w2f = w1f + (size_t)127 * 4096;
    unsigned long long* m64 = (unsigned long long*)((char*)d_ws + 3653632);

    mask_k<<<dim3(64), dim3(256), 0, stream>>>(mask, m64, out);
    embed_k<<<dim3(384), dim3(256), 0, stream>>>(values, times, omega, alpha, zh);
    wprep_k<<<dim3(127), dim3(256), 0, stream>>>(W1, w1f);
    wprep_k<<<dim3(127), dim3(256), 0, stream>>>(W2, w2f);
    filter_k<<<dim3(NSEQ / NCH, 32), dim3(256), 0, stream>>>(zh, m64, w1f, w2f, b1, b2, out);
}